// Round 8
// baseline (792.075 us; speedup 1.0000x reference)
//
#include <hip/hip_runtime.h>
#include <hip/hip_fp16.h>

#define NN    20000
#define NE    150000
#define HD    256
#define NT    4
#define NR    8
#define NH    8
#define DKq   32
#define NL    2
#define MAXL  240
#define HBLK  256
#define SCB   ((NN + 255)/256)
#define INV_SQRT_DK 0.17677669529663687f

typedef _Float16 f16x4 __attribute__((ext_vector_type(4)));
typedef float    f32x4v __attribute__((ext_vector_type(4)));

// ---------- node bucketing (by type), block-local histogram ----------
__global__ __launch_bounds__(256) void k_nhist(const int* __restrict__ ntype, int* __restrict__ nhist)
{
    __shared__ int h[NT];
    const int tid = threadIdx.x, b = blockIdx.x;
    if (tid < NT) h[tid] = 0;
    __syncthreads();
    const int cn = (NN + HBLK-1)/HBLK;
    const int nEnd = min((b+1)*cn, NN);
    for (int i = b*cn + tid; i < nEnd; i += 256) atomicAdd(&h[ntype[i]], 1);
    __syncthreads();
    if (tid < NT) nhist[b*NT + tid] = h[tid];
}
__global__ void k_nscan(const int* __restrict__ nhist, int* __restrict__ noff, int* __restrict__ nbase)
{
    __shared__ int tot[NT];
    const int tid = threadIdx.x;
    if (tid < NT){
        int s = 0;
        for (int b = 0; b < HBLK; b++) s += nhist[b*NT + tid];
        tot[tid] = s;
    }
    __syncthreads();
    if (tid == 0){ noff[0]=0; for (int t=0;t<NT;t++) noff[t+1]=noff[t]+tot[t]; }
    if (tid < NT){
        int base = 0; for (int t=0;t<tid;t++) base += tot[t];
        int run = 0;
        for (int b=0;b<HBLK;b++){ nbase[b*NT+tid] = base + run; run += nhist[b*NT+tid]; }
    }
}
__global__ __launch_bounds__(256) void k_nscatter(const int* __restrict__ ntype,
    const int* __restrict__ nbase, int* __restrict__ nbucket)
{
    __shared__ int cur[NT];
    const int tid = threadIdx.x, b = blockIdx.x;
    if (tid < NT) cur[tid] = nbase[b*NT + tid];
    __syncthreads();
    const int cn = (NN + HBLK-1)/HBLK;
    const int nEnd = min((b+1)*cn, NN);
    for (int i = b*cn + tid; i < nEnd; i += 256)
        nbucket[atomicAdd(&cur[ntype[i]], 1)] = i;
}

// ---------- edge CSR build: sort by tgt ----------
__global__ void k_zero_bins(int* __restrict__ cnt){
    int i = blockIdx.x*256 + threadIdx.x;
    if (i < NN) cnt[i] = 0;
}
__global__ void k_csr_hist(const int* __restrict__ ei, int* __restrict__ cnt){
    int e = blockIdx.x*256 + threadIdx.x;
    if (e >= NE) return;
    atomicAdd(&cnt[ei[NE+e]], 1);
}
__global__ __launch_bounds__(256) void k_scan1(const int* __restrict__ cnt,
    int* __restrict__ tgt_off, int* __restrict__ bsum)
{
    __shared__ int sh[256];
    const int t = threadIdx.x, b = blockIdx.x;
    const int i = b*256 + t;
    const int v = (i < NN) ? cnt[i] : 0;
    sh[t] = v;
    __syncthreads();
    #pragma unroll
    for (int d = 1; d < 256; d <<= 1){
        const int u = (t >= d) ? sh[t-d] : 0;
        __syncthreads();
        sh[t] += u;
        __syncthreads();
    }
    if (i < NN) tgt_off[i] = sh[t] - v;
    if (t == 255) bsum[b] = sh[255];
}
__global__ __launch_bounds__(128) void k_scan2(const int* __restrict__ bsum,
    int* __restrict__ bbase, int* __restrict__ tgt_off)
{
    __shared__ int sh[128];
    const int t = threadIdx.x;
    const int v = (t < SCB) ? bsum[t] : 0;
    sh[t] = v;
    __syncthreads();
    #pragma unroll
    for (int d = 1; d < 128; d <<= 1){
        const int u = (t >= d) ? sh[t-d] : 0;
        __syncthreads();
        sh[t] += u;
        __syncthreads();
    }
    if (t < SCB) bbase[t] = sh[t] - v;
    if (t == 0) tgt_off[NN] = NE;
}
__global__ __launch_bounds__(256) void k_scan3(int* __restrict__ tgt_off,
    const int* __restrict__ bbase, int* __restrict__ binCur)
{
    const int i = blockIdx.x*256 + threadIdx.x;
    if (i >= NN) return;
    const int o = tgt_off[i] + bbase[blockIdx.x];
    tgt_off[i] = o;
    binCur[i] = o;
}
__global__ void k_csr_scatter(const int* __restrict__ ei, const int* __restrict__ etype,
    const int* __restrict__ etime, const int* __restrict__ ntype,
    int* __restrict__ binCur, int* __restrict__ src_s, int* __restrict__ combo_s,
    int* __restrict__ eid_s, int* __restrict__ tgt_s)
{
    int e = blockIdx.x*256 + threadIdx.x;
    if (e >= NE) return;
    const int tgt = ei[NE+e], r = etype[e], src = ei[e];
    const int pos = atomicAdd(&binCur[tgt], 1);
    src_s[pos] = src;
    combo_s[pos] = (etime[e]*NT + ntype[src]) | (r << 12);
    eid_s[pos] = e;
    tgt_s[pos] = tgt;
}

// ---------- weight pre-pack: f32 [K][C] -> f16 fragment-major [(k>>2)*C + c][k&3] ----------
// grid (K*C/1024, nmat), block 256. Per-mat element count = gridDim.x*1024. lc = log2(C).
__global__ __launch_bounds__(256) void k_w2f16(
    const float* __restrict__ in, _Float16* __restrict__ out, int lc)
{
    const size_t msz = (size_t)gridDim.x * 1024;
    const float* ip = in + (size_t)blockIdx.y * msz;
    _Float16* op = out + (size_t)blockIdx.y * msz;
    const int tid4 = blockIdx.x*256 + threadIdx.x;
    const int C = 1 << lc;
    const int k4 = tid4 >> lc, c = tid4 & (C-1);
    f16x4 hv;
    #pragma unroll
    for (int j = 0; j < 4; j++)
        hv[j] = (_Float16)ip[(size_t)(((k4*4 + j) << lc) + c)];
    *reinterpret_cast<f16x4*>(&op[(size_t)tid4 * 4]) = hv;
}

// ---------- typed MFMA GEMM: out_sel[node] = act( in[node] @ Wsel[type] + bsel[type] ) ----------
// W in fragment-major f16 (k_w2f16). block 256 = 4 waves; tile 64x64; K=256.
// grid (nColTiles, ceil/64, NT); nColTiles = 12 for fused QKV (sel = ct>>2), 4 for single.
__global__ __launch_bounds__(256) void k_typed_mfma(
    const float* __restrict__ in,
    const _Float16* __restrict__ W0, const _Float16* __restrict__ W1, const _Float16* __restrict__ W2,
    const float* __restrict__ b0, const float* __restrict__ b1, const float* __restrict__ b2,
    float* __restrict__ o0, float* __restrict__ o1, float* __restrict__ o2,
    const int* __restrict__ nbucket, const int* __restrict__ noff,
    int mode, const float* __restrict__ skipv, const float* __restrict__ xold)
{
    const int t = blockIdx.z;
    const int start = noff[t], cnt = noff[t+1] - start;
    const int rowTile = blockIdx.y;
    if (rowTile*64 >= cnt) return;
    const int ct = blockIdx.x;
    const int sel = ct >> 2;
    const _Float16* W = (sel==0 ? W0 : (sel==1 ? W1 : W2)) + (size_t)t*HD*HD;
    const float* bias = (sel==0 ? b0 : (sel==1 ? b1 : b2)) + (size_t)t*HD;
    float* out = (sel==0 ? o0 : (sel==1 ? o1 : o2));
    const int n0 = (ct & 3)*64;

    const int tid = threadIdx.x;
    const int w = tid >> 6, lane = tid & 63;
    const int lrow = lane & 15, lgrp = lane >> 4;

    __shared__ _Float16 Al[64][260];   // 520B row stride: b64 frag reads hit 32 distinct banks
    __shared__ int nid[64];

    if (tid < 64){
        const int gr = rowTile*64 + tid;
        nid[tid] = (gr < cnt) ? nbucket[start + gr] : -1;
    }
    __syncthreads();

    // stage A (f32 -> f16)
    {
        const int arow = nid[tid & 63];
        const int cc0 = (tid >> 6)*64;
        const float* ap = (arow >= 0) ? (in + (size_t)arow*HD + cc0) : nullptr;
        #pragma unroll
        for (int kk = 0; kk < 16; kk++){
            float4 v = make_float4(0.f,0.f,0.f,0.f);
            if (ap) v = *reinterpret_cast<const float4*>(ap + kk*4);
            f16x4 hv;
            hv[0]=(_Float16)v.x; hv[1]=(_Float16)v.y; hv[2]=(_Float16)v.z; hv[3]=(_Float16)v.w;
            *reinterpret_cast<f16x4*>(&Al[tid & 63][cc0 + kk*4]) = hv;
        }
    }

    // W-frags: coalesced 8B loads from fragment-major table
    f16x4 bfrag[16];
    {
        const int col = n0 + w*16 + lrow;
        #pragma unroll
        for (int kc = 0; kc < 16; kc++)
            bfrag[kc] = *reinterpret_cast<const f16x4*>(&W[(size_t)((kc*4 + lgrp)*HD + col)*4]);
    }
    __syncthreads();

    f32x4v acc[4] = {{0.f,0.f,0.f,0.f},{0.f,0.f,0.f,0.f},{0.f,0.f,0.f,0.f},{0.f,0.f,0.f,0.f}};
    #pragma unroll
    for (int kc = 0; kc < 16; kc++){
        #pragma unroll
        for (int rt = 0; rt < 4; rt++){
            const f16x4 a = *reinterpret_cast<const f16x4*>(&Al[rt*16 + lrow][kc*16 + lgrp*4]);
            acc[rt] = __builtin_amdgcn_mfma_f32_16x16x16f16(a, bfrag[kc], acc[rt], 0,0,0);
        }
    }

    const int col = n0 + w*16 + lrow;
    const float bcol = bias[col];
    float sk = 0.f;
    if (mode == 2) sk = 1.f/(1.f + __expf(-skipv[t]));
    #pragma unroll
    for (int rt = 0; rt < 4; rt++){
        #pragma unroll
        for (int i = 0; i < 4; i++){
            const int lr = rt*16 + lgrp*4 + i;
            const int gr = rowTile*64 + lr;
            if (gr >= cnt) continue;
            const int node = nid[lr];
            float v = acc[rt][i] + bcol;
            if (mode == 1) v = tanhf(v);
            else if (mode == 2){
                const float xo = xold[(size_t)node*HD + col];
                v = v*sk + xo*(1.f - sk);
            }
            out[(size_t)node*HD + col] = v;
        }
    }
}

// ---------- small row GEMM: C[row, ty] = A[row] @ W[ty] (+bias) ----------
__global__ __launch_bounds__(256) void k_row_gemm(
    const float* __restrict__ A, const float* __restrict__ Wb, const float* __restrict__ bias,
    float* __restrict__ C, int c_stride)
{
    const int row = blockIdx.x, ty = blockIdx.y, d = threadIdx.x;
    const float* W = Wb + (size_t)ty*HD*HD;
    __shared__ float ar[HD];
    ar[d] = A[(size_t)row*HD + d];
    __syncthreads();
    float acc = bias ? bias[d] : 0.f;
    #pragma unroll 8
    for (int k=0;k<HD;k++) acc = fmaf(ar[k], W[(size_t)k*HD + d], acc);
    C[(size_t)row*c_stride + ty*HD + d] = acc;
}

// ---------- MFMA fold: OUT[m][r][h*32+c] = sum_d IN[m][h*32+d] * MAT[r][h][d][c] (fp16 out) ----------
// MATF in fragment-major f16 (per (r,h) 32x32 matrix, 1024 halves).
__global__ __launch_bounds__(256) void k_fold_mfma(
    const float* __restrict__ IN, const _Float16* __restrict__ MATF,
    __half* __restrict__ OUT, int M)
{
    const int r = blockIdx.y;
    const int lane = threadIdx.x & 63, w = threadIdx.x >> 6;
    const int lrow = lane & 15, lgrp = lane >> 4;
    f16x4 b[NH][2][2];
    const _Float16* Mr = MATF + (size_t)r*NH*1024;
    #pragma unroll
    for (int h = 0; h < NH; h++)
      #pragma unroll
      for (int kb = 0; kb < 2; kb++)
        #pragma unroll
        for (int hf = 0; hf < 2; hf++)
            b[h][kb][hf] = *reinterpret_cast<const f16x4*>(
                &Mr[(size_t)h*1024 + (size_t)(((kb*4 + lgrp)*32) + hf*16 + lrow)*4]);
    const int ntiles = M >> 4;
    for (int t = blockIdx.x*4 + w; t < ntiles; t += gridDim.x*4){
        const int row0 = t*16;
        const float* inrow = IN + (size_t)(row0 + lrow)*HD;
        f16x4 a[NH][2];
        #pragma unroll
        for (int h = 0; h < NH; h++)
          #pragma unroll
          for (int kb = 0; kb < 2; kb++){
              const float4 v = *reinterpret_cast<const float4*>(&inrow[h*32 + kb*16 + lgrp*4]);
              f16x4 aa;
              aa[0]=(_Float16)v.x; aa[1]=(_Float16)v.y; aa[2]=(_Float16)v.z; aa[3]=(_Float16)v.w;
              a[h][kb] = aa;
          }
        #pragma unroll
        for (int h = 0; h < NH; h++){
          #pragma unroll
          for (int hf = 0; hf < 2; hf++){
              f32x4v acc = {0.f,0.f,0.f,0.f};
              acc = __builtin_amdgcn_mfma_f32_16x16x16f16(a[h][0], b[h][0][hf], acc, 0,0,0);
              acc = __builtin_amdgcn_mfma_f32_16x16x16f16(a[h][1], b[h][1][hf], acc, 0,0,0);
              #pragma unroll
              for (int i = 0; i < 4; i++){
                  const int rr = lgrp*4 + i;
                  OUT[((size_t)(row0+rr)*NR + r)*HD + h*32 + hf*16 + lrow] = __float2half(acc[i]);
              }
          }
        }
    }
}

// ---------- edge scores (streaming, wave per edge) ----------
__global__ __launch_bounds__(256) void k_score(
    const float* __restrict__ q0, const __half* __restrict__ kA, const __half* __restrict__ KcA,
    const float* __restrict__ relP,
    const int* __restrict__ src_s, const int* __restrict__ combo_s, const int* __restrict__ tgt_s,
    float* __restrict__ s_arr)
{
    const int j = blockIdx.x*4 + (threadIdx.x >> 6);
    if (j >= NE) return;
    const int lane = threadIdx.x & 63;
    const int h = lane >> 3, c4 = (lane & 7) << 2;
    const int src = src_s[j];
    const int cw  = combo_s[j];
    const int tgt = tgt_s[j];
    const int r = cw >> 12, combo = cw & 0xFFF;

    const float4 q4 = *reinterpret_cast<const float4*>(&q0[(size_t)tgt*HD + h*32 + c4]);
    const __half2* ka = reinterpret_cast<const __half2*>(&kA[((size_t)src*NR + r)*HD + h*32 + c4]);
    const __half2* kc = reinterpret_cast<const __half2*>(&KcA[((size_t)combo*NR + r)*HD + h*32 + c4]);
    const float2 k0f = __half22float2(ka[0]), k1f = __half22float2(ka[1]);
    const float2 c0f = __half22float2(kc[0]), c1f = __half22float2(kc[1]);
    float v = q4.x*(k0f.x+c0f.x) + q4.y*(k0f.y+c0f.y) + q4.z*(k1f.x+c1f.x) + q4.w*(k1f.y+c1f.y);
    v += __shfl_xor(v, 1); v += __shfl_xor(v, 2); v += __shfl_xor(v, 4);
    if ((lane & 7) == 0)
        s_arr[(size_t)j*NH + h] = v * relP[r*NH + h] * INV_SQRT_DK;
}

// ---------- node-parallel segment softmax (CSR) ----------
__global__ __launch_bounds__(256) void k_softmax(
    float* __restrict__ s_arr, const int* __restrict__ tgt_off, const int* __restrict__ eid_s,
    float* __restrict__ out_att, int store)
{
    const int idx = blockIdx.x*256 + threadIdx.x;
    if (idx >= NN*NH) return;
    const int n = idx >> 3, h = idx & 7;
    const int e0 = tgt_off[n], e1 = tgt_off[n+1];
    if (e0 == e1) return;
    float m = -INFINITY;
    for (int j = e0; j < e1; j++) m = fmaxf(m, s_arr[(size_t)j*NH + h]);
    float l = 0.f;
    for (int j = e0; j < e1; j++) l += __expf(s_arr[(size_t)j*NH + h] - m);
    const float inv = 1.f / l;
    for (int j = e0; j < e1; j++){
        const float a = __expf(s_arr[(size_t)j*NH + h] - m) * inv;
        s_arr[(size_t)j*NH + h] = a;
        if (store) out_att[(size_t)eid_s[j]*NH + h] = a;
    }
}

// ---------- aggregation (CSR, wave per node), gelu fused ----------
__global__ __launch_bounds__(256) void k_agg(
    const __half* __restrict__ vM, const __half* __restrict__ VcM,
    const float* __restrict__ alpha,
    const int* __restrict__ tgt_off, const int* __restrict__ src_s, const int* __restrict__ combo_s,
    float* __restrict__ agg)
{
    const int n = blockIdx.x*4 + (threadIdx.x >> 6);
    if (n >= NN) return;
    const int lane = threadIdx.x & 63;
    const int h = lane >> 3, c4 = (lane & 7) << 2;
    const int col = h*32 + c4;
    const int e0 = tgt_off[n], e1 = tgt_off[n+1];
    float a0=0.f, a1=0.f, a2=0.f, a3=0.f;
    for (int j = e0; j < e1; j++){
        const int src = src_s[j];
        const int cw  = combo_s[j];
        const int r = cw >> 12, combo = cw & 0xFFF;
        const float al = alpha[(size_t)j*NH + h];
        const __half2* vm = reinterpret_cast<const __half2*>(&vM[((size_t)src*NR + r)*HD + col]);
        const __half2* vc = reinterpret_cast<const __half2*>(&VcM[((size_t)combo*NR + r)*HD + col]);
        const float2 v0f = __half22float2(vm[0]), v1f = __half22float2(vm[1]);
        const float2 c0f = __half22float2(vc[0]), c1f = __half22float2(vc[1]);
        a0 = fmaf(al, v0f.x + c0f.x, a0);
        a1 = fmaf(al, v0f.y + c0f.y, a1);
        a2 = fmaf(al, v1f.x + c1f.x, a2);
        a3 = fmaf(al, v1f.y + c1f.y, a3);
    }
    float4 o;
    o.x = 0.5f*a0*(1.f + erff(a0*0.70710678118654752f));
    o.y = 0.5f*a1*(1.f + erff(a1*0.70710678118654752f));
    o.z = 0.5f*a2*(1.f + erff(a2*0.70710678118654752f));
    o.w = 0.5f*a3*(1.f + erff(a3*0.70710678118654752f));
    *reinterpret_cast<float4*>(&agg[(size_t)n*HD + col]) = o;
}

__global__ void k_copy(const float* __restrict__ s, float* __restrict__ d, int n){
    int i = blockIdx.x*256 + threadIdx.x;
    if (i < n) d[i] = s[i];
}

extern "C" void kernel_launch(void* const* d_in, const int* in_sizes, int n_in,
                              void* d_out, int out_size, void* d_ws, size_t ws_size,
                              hipStream_t stream)
{
    const float* node_feature = (const float*)d_in[0];
    const int*   node_type    = (const int*)d_in[1];
    const int*   edge_time    = (const int*)d_in[2];
    const int*   edge_index   = (const int*)d_in[3];
    const int*   edge_type    = (const int*)d_in[4];
    const float* adapt_W = (const float*)d_in[5];
    const float* adapt_b = (const float*)d_in[6];
    const float* k_W = (const float*)d_in[7];
    const float* k_b = (const float*)d_in[8];
    const float* q_W = (const float*)d_in[9];
    const float* q_b = (const float*)d_in[10];
    const float* v_W = (const float*)d_in[11];
    const float* v_b = (const float*)d_in[12];
    const float* a_W = (const float*)d_in[13];
    const float* a_b = (const float*)d_in[14];
    const float* rel_pri = (const float*)d_in[15];
    const float* rel_att = (const float*)d_in[16];
    const float* rel_msg = (const float*)d_in[17];
    const float* skip  = (const float*)d_in[18];
    const float* rte_W = (const float*)d_in[19];
    const float* rte_b = (const float*)d_in[20];
    const float* rte_emb = (const float*)d_in[21];

    char* wp = (char*)d_ws;
    auto alloc_f = [&](size_t n)->float*{ float* p=(float*)wp; wp += n*sizeof(float); return p; };
    auto alloc_i = [&](size_t n)->int*  { int*   p=(int*)wp;   wp += n*sizeof(int);   return p; };
    auto alloc_h = [&](size_t n)->_Float16*{ _Float16* p=(_Float16*)wp; wp += n*sizeof(_Float16); return p; };
    float* xA    = alloc_f((size_t)NN*HD);
    float* xB    = alloc_f((size_t)NN*HD);
    float* q0    = alloc_f((size_t)NN*HD);
    float* k0    = alloc_f((size_t)NN*HD);
    float* v0    = alloc_f((size_t)NN*HD);
    float* agg   = alloc_f((size_t)NN*HD);
    float* s_arr = alloc_f((size_t)NE*NH);
    float* rteP  = alloc_f((size_t)MAXL*HD);
    float* Kc    = alloc_f((size_t)MAXL*NT*HD);
    float* Vc    = alloc_f((size_t)MAXL*NT*HD);
    _Float16* kavm = alloc_h((size_t)NN*NR*HD);        // kA then reused for vM
    _Float16* kca  = alloc_h((size_t)MAXL*NT*NR*HD);   // KcA then reused for VcM
    _Float16* adaptF = alloc_h((size_t)NT*HD*HD);
    _Float16* qF   = alloc_h((size_t)NL*NT*HD*HD);
    _Float16* kF   = alloc_h((size_t)NL*NT*HD*HD);
    _Float16* vF   = alloc_h((size_t)NL*NT*HD*HD);
    _Float16* aF   = alloc_h((size_t)NL*NT*HD*HD);
    _Float16* relAF = alloc_h((size_t)NL*NR*NH*DKq*DKq);
    _Float16* relMF = alloc_h((size_t)NL*NR*NH*DKq*DKq);
    int* nbucket = alloc_i(NN);
    int* nhist   = alloc_i(HBLK*NT);
    int* nbase   = alloc_i(HBLK*NT);
    int* noff    = alloc_i(8);
    int* cnt     = alloc_i(NN);
    int* bsum    = alloc_i(SCB);
    int* bbase   = alloc_i(SCB);
    int* binCur  = alloc_i(NN);
    int* tgt_off = alloc_i(NN+1);
    int* src_s   = alloc_i(NE);
    int* combo_s = alloc_i(NE);
    int* eid_s   = alloc_i(NE);
    int* tgt_s   = alloc_i(NE);

    float* out_att = (float*)d_out;
    float* out_x   = (float*)d_out + (size_t)NE*NH;

    const int rowTiles = (NN + 63)/64;
    const dim3 gQKV(12, rowTiles, NT);
    const dim3 gT1(4, rowTiles, NT);
    const dim3 gFoldN(79, NR);
    const dim3 gFoldC(15, NR);
    const int gE256 = (NE + 255)/256;
    const int gNH = (NN*HD + 255)/256;
    const int gSc = (NE + 3)/4;
    const int gSm = (NN*NH + 255)/256;
    const int gAg = (NN + 3)/4;

    // weight pre-pack to f16 fragment-major (once)
    k_w2f16<<<dim3(64, NT),       256,0,stream>>>(adapt_W, adaptF, 8);
    k_w2f16<<<dim3(64, NL*NT),    256,0,stream>>>(q_W, qF, 8);
    k_w2f16<<<dim3(64, NL*NT),    256,0,stream>>>(k_W, kF, 8);
    k_w2f16<<<dim3(64, NL*NT),    256,0,stream>>>(v_W, vF, 8);
    k_w2f16<<<dim3(64, NL*NT),    256,0,stream>>>(a_W, aF, 8);
    k_w2f16<<<dim3(1, NL*NR*NH),  256,0,stream>>>(rel_att, relAF, 5);
    k_w2f16<<<dim3(1, NL*NR*NH),  256,0,stream>>>(rel_msg, relMF, 5);

    // node buckets (by type)
    k_nhist<<<HBLK,256,0,stream>>>(node_type, nhist);
    k_nscan<<<1,64,0,stream>>>(nhist, noff, nbase);
    k_nscatter<<<HBLK,256,0,stream>>>(node_type, nbase, nbucket);

    // edge CSR sorted by tgt (parallel 3-phase scan)
    k_zero_bins<<<SCB,256,0,stream>>>(cnt);
    k_csr_hist<<<gE256,256,0,stream>>>(edge_index, cnt);
    k_scan1<<<SCB,256,0,stream>>>(cnt, tgt_off, bsum);
    k_scan2<<<1,128,0,stream>>>(bsum, bbase, tgt_off);
    k_scan3<<<SCB,256,0,stream>>>(tgt_off, bbase, binCur);
    k_csr_scatter<<<gE256,256,0,stream>>>(edge_index, edge_type, edge_time, node_type,
                                          binCur, src_s, combo_s, eid_s, tgt_s);

    // adapt: x = tanh(node_feature @ adapt_W[t] + b)  (MFMA)
    k_typed_mfma<<<gT1,256,0,stream>>>(node_feature, adaptF, nullptr, nullptr,
                                       adapt_b, nullptr, nullptr,
                                       xA, nullptr, nullptr,
                                       nbucket, noff, 1, nullptr, nullptr);

    const float* x_in = xA;
    float* x_out = xB;
    for (int l = 0; l < NL; l++){
        k_row_gemm<<<dim3(MAXL,1),256,0,stream>>>(rte_emb, rte_W + (size_t)l*HD*HD,
                                                  rte_b + (size_t)l*HD, rteP, HD);
        k_row_gemm<<<dim3(MAXL,NT),256,0,stream>>>(rteP, k_W + (size_t)l*NT*HD*HD, nullptr, Kc, NT*HD);
        k_row_gemm<<<dim3(MAXL,NT),256,0,stream>>>(rteP, v_W + (size_t)l*NT*HD*HD, nullptr, Vc, NT*HD);
        // fused Q/K/V node-level GEMM (MFMA)
        k_typed_mfma<<<gQKV,256,0,stream>>>(x_in,
                                            qF + (size_t)l*NT*HD*HD, kF + (size_t)l*NT*HD*HD, vF + (size_t)l*NT*HD*HD,
                                            q_b + (size_t)l*NT*HD,  k_b + (size_t)l*NT*HD,  v_b + (size_t)l*NT*HD,
                                            q0, k0, v0,
                                            nbucket, noff, 0, nullptr, nullptr);
        // fold rel_att into node-level and combo-level tables (MFMA)
        k_fold_mfma<<<gFoldN,256,0,stream>>>(k0, relAF + (size_t)l*NR*NH*1024, (__half*)kavm, NN);
        k_fold_mfma<<<gFoldC,256,0,stream>>>(Kc, relAF + (size_t)l*NR*NH*1024, (__half*)kca, MAXL*NT);
        // scores + softmax
        k_score<<<gSc,256,0,stream>>>(q0, (__half*)kavm, (__half*)kca, rel_pri + (size_t)l*NR*NH,
                                      src_s, combo_s, tgt_s, s_arr);
        const int store_s = (l == NL-1) ? 1 : 0;
        k_softmax<<<gSm,256,0,stream>>>(s_arr, tgt_off, eid_s, out_att, store_s);
        // fold rel_msg, then aggregate (+gelu)
        k_fold_mfma<<<gFoldN,256,0,stream>>>(v0, relMF + (size_t)l*NR*NH*1024, (__half*)kavm, NN);
        k_fold_mfma<<<gFoldC,256,0,stream>>>(Vc, relMF + (size_t)l*NR*NH*1024, (__half*)kca, MAXL*NT);
        k_agg<<<gAg,256,0,stream>>>((__half*)kavm, (__half*)kca, s_arr, tgt_off, src_s, combo_s, agg);
        // output transform + skip (MFMA)
        k_typed_mfma<<<gT1,256,0,stream>>>(agg, aF + (size_t)l*NT*HD*HD, nullptr, nullptr,
                                           a_b + (size_t)l*NT*HD, nullptr, nullptr,
                                           x_out, nullptr, nullptr,
                                           nbucket, noff, 2, skip + (size_t)l*NT, x_in);
        float* tmp = (float*)x_in; x_in = x_out; x_out = tmp;
    }
    k_copy<<<gNH,256,0,stream>>>(x_in, out_x, NN*HD);
}

// Round 9
// 709.844 us; speedup vs baseline: 1.1158x; 1.1158x over previous
//
#include <hip/hip_runtime.h>
#include <hip/hip_fp16.h>

#define NN    20000
#define NE    150000
#define HD    256
#define NT    4
#define NR    8
#define NH    8
#define DKq   32
#define NL    2
#define MAXL  240
#define HBLK  256
#define SCB   ((NN + 255)/256)
#define INV_SQRT_DK 0.17677669529663687f

typedef _Float16 f16x4 __attribute__((ext_vector_type(4)));
typedef float    f32x4v __attribute__((ext_vector_type(4)));

// ---------- node bucketing (by type), block-local histogram ----------
__global__ __launch_bounds__(256) void k_nhist(const int* __restrict__ ntype, int* __restrict__ nhist)
{
    __shared__ int h[NT];
    const int tid = threadIdx.x, b = blockIdx.x;
    if (tid < NT) h[tid] = 0;
    __syncthreads();
    const int cn = (NN + HBLK-1)/HBLK;
    const int nEnd = min((b+1)*cn, NN);
    for (int i = b*cn + tid; i < nEnd; i += 256) atomicAdd(&h[ntype[i]], 1);
    __syncthreads();
    if (tid < NT) nhist[b*NT + tid] = h[tid];
}
__global__ void k_nscan(const int* __restrict__ nhist, int* __restrict__ noff, int* __restrict__ nbase)
{
    __shared__ int tot[NT];
    const int tid = threadIdx.x;
    if (tid < NT){
        int s = 0;
        for (int b = 0; b < HBLK; b++) s += nhist[b*NT + tid];
        tot[tid] = s;
    }
    __syncthreads();
    if (tid == 0){ noff[0]=0; for (int t=0;t<NT;t++) noff[t+1]=noff[t]+tot[t]; }
    if (tid < NT){
        int base = 0; for (int t=0;t<tid;t++) base += tot[t];
        int run = 0;
        for (int b=0;b<HBLK;b++){ nbase[b*NT+tid] = base + run; run += nhist[b*NT+tid]; }
    }
}
__global__ __launch_bounds__(256) void k_nscatter(const int* __restrict__ ntype,
    const int* __restrict__ nbase, int* __restrict__ nbucket)
{
    __shared__ int cur[NT];
    const int tid = threadIdx.x, b = blockIdx.x;
    if (tid < NT) cur[tid] = nbase[b*NT + tid];
    __syncthreads();
    const int cn = (NN + HBLK-1)/HBLK;
    const int nEnd = min((b+1)*cn, NN);
    for (int i = b*cn + tid; i < nEnd; i += 256)
        nbucket[atomicAdd(&cur[ntype[i]], 1)] = i;
}

// ---------- edge CSR build: sort by tgt ----------
__global__ void k_zero_bins(int* __restrict__ cnt){
    int i = blockIdx.x*256 + threadIdx.x;
    if (i < NN) cnt[i] = 0;
}
__global__ void k_csr_hist(const int* __restrict__ ei, int* __restrict__ cnt){
    int e = blockIdx.x*256 + threadIdx.x;
    if (e >= NE) return;
    atomicAdd(&cnt[ei[NE+e]], 1);
}
__global__ __launch_bounds__(256) void k_scan1(const int* __restrict__ cnt,
    int* __restrict__ tgt_off, int* __restrict__ bsum)
{
    __shared__ int sh[256];
    const int t = threadIdx.x, b = blockIdx.x;
    const int i = b*256 + t;
    const int v = (i < NN) ? cnt[i] : 0;
    sh[t] = v;
    __syncthreads();
    #pragma unroll
    for (int d = 1; d < 256; d <<= 1){
        const int u = (t >= d) ? sh[t-d] : 0;
        __syncthreads();
        sh[t] += u;
        __syncthreads();
    }
    if (i < NN) tgt_off[i] = sh[t] - v;
    if (t == 255) bsum[b] = sh[255];
}
__global__ __launch_bounds__(128) void k_scan2(const int* __restrict__ bsum,
    int* __restrict__ bbase, int* __restrict__ tgt_off)
{
    __shared__ int sh[128];
    const int t = threadIdx.x;
    const int v = (t < SCB) ? bsum[t] : 0;
    sh[t] = v;
    __syncthreads();
    #pragma unroll
    for (int d = 1; d < 128; d <<= 1){
        const int u = (t >= d) ? sh[t-d] : 0;
        __syncthreads();
        sh[t] += u;
        __syncthreads();
    }
    if (t < SCB) bbase[t] = sh[t] - v;
    if (t == 0) tgt_off[NN] = NE;
}
__global__ __launch_bounds__(256) void k_scan3(int* __restrict__ tgt_off,
    const int* __restrict__ bbase, int* __restrict__ binCur)
{
    const int i = blockIdx.x*256 + threadIdx.x;
    if (i >= NN) return;
    const int o = tgt_off[i] + bbase[blockIdx.x];
    tgt_off[i] = o;
    binCur[i] = o;
}
__global__ void k_csr_scatter(const int* __restrict__ ei, const int* __restrict__ etype,
    const int* __restrict__ etime, const int* __restrict__ ntype,
    int* __restrict__ binCur, int* __restrict__ src_s, int* __restrict__ combo_s,
    int* __restrict__ eid_s, int* __restrict__ tgt_s)
{
    int e = blockIdx.x*256 + threadIdx.x;
    if (e >= NE) return;
    const int tgt = ei[NE+e], r = etype[e], src = ei[e];
    const int pos = atomicAdd(&binCur[tgt], 1);
    src_s[pos] = src;
    combo_s[pos] = (etime[e]*NT + ntype[src]) | (r << 12);
    eid_s[pos] = e;
    tgt_s[pos] = tgt;
}

// ---------- weight pre-pack: f32 [K][C] -> f16 fragment-major [(k>>2)*C + c][k&3] ----------
__global__ __launch_bounds__(256) void k_w2f16(
    const float* __restrict__ in, _Float16* __restrict__ out, int lc)
{
    const size_t msz = (size_t)gridDim.x * 1024;
    const float* ip = in + (size_t)blockIdx.y * msz;
    _Float16* op = out + (size_t)blockIdx.y * msz;
    const int tid4 = blockIdx.x*256 + threadIdx.x;
    const int C = 1 << lc;
    const int k4 = tid4 >> lc, c = tid4 & (C-1);
    f16x4 hv;
    #pragma unroll
    for (int j = 0; j < 4; j++)
        hv[j] = (_Float16)ip[(size_t)(((k4*4 + j) << lc) + c)];
    *reinterpret_cast<f16x4*>(&op[(size_t)tid4 * 4]) = hv;
}

// ---------- typed MFMA GEMM: one block = one 64-row tile, ALL 256 cols, all nsel outputs ----------
// A staged once in LDS; wave w owns cols [w*64, w*64+64), 4 col-subtiles of 16.
// grid (rowTiles, NT). mode 0: bias; 1: tanh; 2: skip-combine.
__global__ __launch_bounds__(256) void k_typed_mfma(
    const float* __restrict__ in,
    const _Float16* __restrict__ W0, const _Float16* __restrict__ W1, const _Float16* __restrict__ W2,
    const float* __restrict__ b0, const float* __restrict__ b1, const float* __restrict__ b2,
    float* __restrict__ o0, float* __restrict__ o1, float* __restrict__ o2,
    const int* __restrict__ nbucket, const int* __restrict__ noff,
    int nsel, int mode, const float* __restrict__ skipv, const float* __restrict__ xold)
{
    const int t = blockIdx.y;
    const int start = noff[t], cnt = noff[t+1] - start;
    const int rowTile = blockIdx.x;
    if (rowTile*64 >= cnt) return;

    const int tid = threadIdx.x;
    const int w = tid >> 6, lane = tid & 63;
    const int lrow = lane & 15, lgrp = lane >> 4;

    __shared__ _Float16 Al[64][260];
    __shared__ int nid[64];

    if (tid < 64){
        const int gr = rowTile*64 + tid;
        nid[tid] = (gr < cnt) ? nbucket[start + gr] : -1;
    }
    __syncthreads();

    // stage A once (f32 -> f16)
    {
        const int arow = nid[tid & 63];
        const int cc0 = (tid >> 6)*64;
        const float* ap = (arow >= 0) ? (in + (size_t)arow*HD + cc0) : nullptr;
        #pragma unroll
        for (int kk = 0; kk < 16; kk++){
            float4 v = make_float4(0.f,0.f,0.f,0.f);
            if (ap) v = *reinterpret_cast<const float4*>(ap + kk*4);
            f16x4 hv;
            hv[0]=(_Float16)v.x; hv[1]=(_Float16)v.y; hv[2]=(_Float16)v.z; hv[3]=(_Float16)v.w;
            *reinterpret_cast<f16x4*>(&Al[tid & 63][cc0 + kk*4]) = hv;
        }
    }
    __syncthreads();

    float sk = 0.f;
    if (mode == 2) sk = 1.f/(1.f + __expf(-skipv[t]));

    auto proc = [&](const _Float16* Wb, const float* bb, float* out){
        const _Float16* W = Wb + (size_t)t*HD*HD;
        const float* bias = bb + (size_t)t*HD;
        #pragma unroll
        for (int cs = 0; cs < 4; cs++){
            const int col0 = w*64 + cs*16;
            f16x4 bfrag[16];
            #pragma unroll
            for (int kc = 0; kc < 16; kc++)
                bfrag[kc] = *reinterpret_cast<const f16x4*>(
                    &W[(size_t)((kc*4 + lgrp)*HD + col0 + lrow)*4]);
            f32x4v acc[4] = {{0.f,0.f,0.f,0.f},{0.f,0.f,0.f,0.f},
                             {0.f,0.f,0.f,0.f},{0.f,0.f,0.f,0.f}};
            #pragma unroll
            for (int kc = 0; kc < 16; kc++){
                #pragma unroll
                for (int rt = 0; rt < 4; rt++){
                    const f16x4 a = *reinterpret_cast<const f16x4*>(
                        &Al[rt*16 + lrow][kc*16 + lgrp*4]);
                    acc[rt] = __builtin_amdgcn_mfma_f32_16x16x16f16(a, bfrag[kc], acc[rt], 0,0,0);
                }
            }
            const int col = col0 + lrow;
            const float bcol = bias[col];
            #pragma unroll
            for (int rt = 0; rt < 4; rt++){
                #pragma unroll
                for (int i = 0; i < 4; i++){
                    const int lr = rt*16 + lgrp*4 + i;
                    const int gr = rowTile*64 + lr;
                    if (gr >= cnt) continue;
                    const int node = nid[lr];
                    float v = acc[rt][i] + bcol;
                    if (mode == 1) v = tanhf(v);
                    else if (mode == 2){
                        const float xo = xold[(size_t)node*HD + col];
                        v = v*sk + xo*(1.f - sk);
                    }
                    out[(size_t)node*HD + col] = v;
                }
            }
        }
    };

    proc(W0, b0, o0);
    if (nsel > 1){
        proc(W1, b1, o1);
        proc(W2, b2, o2);
    }
}

// ---------- small row GEMM: C[row, ty] = A[row] @ W[ty] (+bias) ----------
__global__ __launch_bounds__(256) void k_row_gemm(
    const float* __restrict__ A, const float* __restrict__ Wb, const float* __restrict__ bias,
    float* __restrict__ C, int c_stride)
{
    const int row = blockIdx.x, ty = blockIdx.y, d = threadIdx.x;
    const float* W = Wb + (size_t)ty*HD*HD;
    __shared__ float ar[HD];
    ar[d] = A[(size_t)row*HD + d];
    __syncthreads();
    float acc = bias ? bias[d] : 0.f;
    #pragma unroll 8
    for (int k=0;k<HD;k++) acc = fmaf(ar[k], W[(size_t)k*HD + d], acc);
    C[(size_t)row*c_stride + ty*HD + d] = acc;
}

// ---------- MFMA fold: OUT[m][r][h*32+c] = sum_d IN[m][h*32+d] * MAT[r][h][d][c] (fp16 out) ----------
__global__ __launch_bounds__(256) void k_fold_mfma(
    const float* __restrict__ IN, const _Float16* __restrict__ MATF,
    __half* __restrict__ OUT, int M)
{
    const int r = blockIdx.y;
    const int lane = threadIdx.x & 63, w = threadIdx.x >> 6;
    const int lrow = lane & 15, lgrp = lane >> 4;
    f16x4 b[NH][2][2];
    const _Float16* Mr = MATF + (size_t)r*NH*1024;
    #pragma unroll
    for (int h = 0; h < NH; h++)
      #pragma unroll
      for (int kb = 0; kb < 2; kb++)
        #pragma unroll
        for (int hf = 0; hf < 2; hf++)
            b[h][kb][hf] = *reinterpret_cast<const f16x4*>(
                &Mr[(size_t)h*1024 + (size_t)(((kb*4 + lgrp)*32) + hf*16 + lrow)*4]);
    const int ntiles = M >> 4;
    for (int t = blockIdx.x*4 + w; t < ntiles; t += gridDim.x*4){
        const int row0 = t*16;
        const float* inrow = IN + (size_t)(row0 + lrow)*HD;
        f16x4 a[NH][2];
        #pragma unroll
        for (int h = 0; h < NH; h++)
          #pragma unroll
          for (int kb = 0; kb < 2; kb++){
              const float4 v = *reinterpret_cast<const float4*>(&inrow[h*32 + kb*16 + lgrp*4]);
              f16x4 aa;
              aa[0]=(_Float16)v.x; aa[1]=(_Float16)v.y; aa[2]=(_Float16)v.z; aa[3]=(_Float16)v.w;
              a[h][kb] = aa;
          }
        #pragma unroll
        for (int h = 0; h < NH; h++){
          #pragma unroll
          for (int hf = 0; hf < 2; hf++){
              f32x4v acc = {0.f,0.f,0.f,0.f};
              acc = __builtin_amdgcn_mfma_f32_16x16x16f16(a[h][0], b[h][0][hf], acc, 0,0,0);
              acc = __builtin_amdgcn_mfma_f32_16x16x16f16(a[h][1], b[h][1][hf], acc, 0,0,0);
              #pragma unroll
              for (int i = 0; i < 4; i++){
                  const int rr = lgrp*4 + i;
                  OUT[((size_t)(row0+rr)*NR + r)*HD + h*32 + hf*16 + lrow] = __float2half(acc[i]);
              }
          }
        }
    }
}

// ---------- edge scores (streaming, wave per edge) ----------
__global__ __launch_bounds__(256) void k_score(
    const float* __restrict__ q0, const __half* __restrict__ kA, const __half* __restrict__ KcA,
    const float* __restrict__ relP,
    const int* __restrict__ src_s, const int* __restrict__ combo_s, const int* __restrict__ tgt_s,
    float* __restrict__ s_arr)
{
    const int j = blockIdx.x*4 + (threadIdx.x >> 6);
    if (j >= NE) return;
    const int lane = threadIdx.x & 63;
    const int h = lane >> 3, c4 = (lane & 7) << 2;
    const int src = src_s[j];
    const int cw  = combo_s[j];
    const int tgt = tgt_s[j];
    const int r = cw >> 12, combo = cw & 0xFFF;

    const float4 q4 = *reinterpret_cast<const float4*>(&q0[(size_t)tgt*HD + h*32 + c4]);
    const __half2* ka = reinterpret_cast<const __half2*>(&kA[((size_t)src*NR + r)*HD + h*32 + c4]);
    const __half2* kc = reinterpret_cast<const __half2*>(&KcA[((size_t)combo*NR + r)*HD + h*32 + c4]);
    const float2 k0f = __half22float2(ka[0]), k1f = __half22float2(ka[1]);
    const float2 c0f = __half22float2(kc[0]), c1f = __half22float2(kc[1]);
    float v = q4.x*(k0f.x+c0f.x) + q4.y*(k0f.y+c0f.y) + q4.z*(k1f.x+c1f.x) + q4.w*(k1f.y+c1f.y);
    v += __shfl_xor(v, 1); v += __shfl_xor(v, 2); v += __shfl_xor(v, 4);
    if ((lane & 7) == 0)
        s_arr[(size_t)j*NH + h] = v * relP[r*NH + h] * INV_SQRT_DK;
}

// ---------- node-parallel segment softmax (CSR) ----------
__global__ __launch_bounds__(256) void k_softmax(
    float* __restrict__ s_arr, const int* __restrict__ tgt_off, const int* __restrict__ eid_s,
    float* __restrict__ out_att, int store)
{
    const int idx = blockIdx.x*256 + threadIdx.x;
    if (idx >= NN*NH) return;
    const int n = idx >> 3, h = idx & 7;
    const int e0 = tgt_off[n], e1 = tgt_off[n+1];
    if (e0 == e1) return;
    float m = -INFINITY;
    for (int j = e0; j < e1; j++) m = fmaxf(m, s_arr[(size_t)j*NH + h]);
    float l = 0.f;
    for (int j = e0; j < e1; j++) l += __expf(s_arr[(size_t)j*NH + h] - m);
    const float inv = 1.f / l;
    for (int j = e0; j < e1; j++){
        const float a = __expf(s_arr[(size_t)j*NH + h] - m) * inv;
        s_arr[(size_t)j*NH + h] = a;
        if (store) out_att[(size_t)eid_s[j]*NH + h] = a;
    }
}

// ---------- aggregation (CSR, wave per node), gelu fused ----------
__global__ __launch_bounds__(256) void k_agg(
    const __half* __restrict__ vM, const __half* __restrict__ VcM,
    const float* __restrict__ alpha,
    const int* __restrict__ tgt_off, const int* __restrict__ src_s, const int* __restrict__ combo_s,
    float* __restrict__ agg)
{
    const int n = blockIdx.x*4 + (threadIdx.x >> 6);
    if (n >= NN) return;
    const int lane = threadIdx.x & 63;
    const int h = lane >> 3, c4 = (lane & 7) << 2;
    const int col = h*32 + c4;
    const int e0 = tgt_off[n], e1 = tgt_off[n+1];
    float a0=0.f, a1=0.f, a2=0.f, a3=0.f;
    for (int j = e0; j < e1; j++){
        const int src = src_s[j];
        const int cw  = combo_s[j];
        const int r = cw >> 12, combo = cw & 0xFFF;
        const float al = alpha[(size_t)j*NH + h];
        const __half2* vm = reinterpret_cast<const __half2*>(&vM[((size_t)src*NR + r)*HD + col]);
        const __half2* vc = reinterpret_cast<const __half2*>(&VcM[((size_t)combo*NR + r)*HD + col]);
        const float2 v0f = __half22float2(vm[0]), v1f = __half22float2(vm[1]);
        const float2 c0f = __half22float2(vc[0]), c1f = __half22float2(vc[1]);
        a0 = fmaf(al, v0f.x + c0f.x, a0);
        a1 = fmaf(al, v0f.y + c0f.y, a1);
        a2 = fmaf(al, v1f.x + c1f.x, a2);
        a3 = fmaf(al, v1f.y + c1f.y, a3);
    }
    float4 o;
    o.x = 0.5f*a0*(1.f + erff(a0*0.70710678118654752f));
    o.y = 0.5f*a1*(1.f + erff(a1*0.70710678118654752f));
    o.z = 0.5f*a2*(1.f + erff(a2*0.70710678118654752f));
    o.w = 0.5f*a3*(1.f + erff(a3*0.70710678118654752f));
    *reinterpret_cast<float4*>(&agg[(size_t)n*HD + col]) = o;
}

__global__ void k_copy(const float* __restrict__ s, float* __restrict__ d, int n){
    int i = blockIdx.x*256 + threadIdx.x;
    if (i < n) d[i] = s[i];
}

extern "C" void kernel_launch(void* const* d_in, const int* in_sizes, int n_in,
                              void* d_out, int out_size, void* d_ws, size_t ws_size,
                              hipStream_t stream)
{
    const float* node_feature = (const float*)d_in[0];
    const int*   node_type    = (const int*)d_in[1];
    const int*   edge_time    = (const int*)d_in[2];
    const int*   edge_index   = (const int*)d_in[3];
    const int*   edge_type    = (const int*)d_in[4];
    const float* adapt_W = (const float*)d_in[5];
    const float* adapt_b = (const float*)d_in[6];
    const float* k_W = (const float*)d_in[7];
    const float* k_b = (const float*)d_in[8];
    const float* q_W = (const float*)d_in[9];
    const float* q_b = (const float*)d_in[10];
    const float* v_W = (const float*)d_in[11];
    const float* v_b = (const float*)d_in[12];
    const float* a_W = (const float*)d_in[13];
    const float* a_b = (const float*)d_in[14];
    const float* rel_pri = (const float*)d_in[15];
    const float* rel_att = (const float*)d_in[16];
    const float* rel_msg = (const float*)d_in[17];
    const float* skip  = (const float*)d_in[18];
    const float* rte_W = (const float*)d_in[19];
    const float* rte_b = (const float*)d_in[20];
    const float* rte_emb = (const float*)d_in[21];

    char* wp = (char*)d_ws;
    auto alloc_f = [&](size_t n)->float*{ float* p=(float*)wp; wp += n*sizeof(float); return p; };
    auto alloc_i = [&](size_t n)->int*  { int*   p=(int*)wp;   wp += n*sizeof(int);   return p; };
    auto alloc_h = [&](size_t n)->_Float16*{ _Float16* p=(_Float16*)wp; wp += n*sizeof(_Float16); return p; };
    float* xA    = alloc_f((size_t)NN*HD);
    float* xB    = alloc_f((size_t)NN*HD);
    float* q0    = alloc_f((size_t)NN*HD);
    float* k0    = alloc_f((size_t)NN*HD);
    float* v0    = alloc_f((size_t)NN*HD);
    float* agg   = alloc_f((size_t)NN*HD);
    float* s_arr = alloc_f((size_t)NE*NH);
    float* rteP  = alloc_f((size_t)MAXL*HD);
    float* Kc    = alloc_f((size_t)MAXL*NT*HD);
    float* Vc    = alloc_f((size_t)MAXL*NT*HD);
    _Float16* kavm = alloc_h((size_t)NN*NR*HD);
    _Float16* kca  = alloc_h((size_t)MAXL*NT*NR*HD);
    _Float16* adaptF = alloc_h((size_t)NT*HD*HD);
    _Float16* qF   = alloc_h((size_t)NL*NT*HD*HD);
    _Float16* kF   = alloc_h((size_t)NL*NT*HD*HD);
    _Float16* vF   = alloc_h((size_t)NL*NT*HD*HD);
    _Float16* aF   = alloc_h((size_t)NL*NT*HD*HD);
    _Float16* relAF = alloc_h((size_t)NL*NR*NH*DKq*DKq);
    _Float16* relMF = alloc_h((size_t)NL*NR*NH*DKq*DKq);
    int* nbucket = alloc_i(NN);
    int* nhist   = alloc_i(HBLK*NT);
    int* nbase   = alloc_i(HBLK*NT);
    int* noff    = alloc_i(8);
    int* cnt     = alloc_i(NN);
    int* bsum    = alloc_i(SCB);
    int* bbase   = alloc_i(SCB);
    int* binCur  = alloc_i(NN);
    int* tgt_off = alloc_i(NN+1);
    int* src_s   = alloc_i(NE);
    int* combo_s = alloc_i(NE);
    int* eid_s   = alloc_i(NE);
    int* tgt_s   = alloc_i(NE);

    float* out_att = (float*)d_out;
    float* out_x   = (float*)d_out + (size_t)NE*NH;

    const int rowTiles = (NN + 63)/64;
    const dim3 gTyp(rowTiles, NT);
    const dim3 gFoldN(79, NR);
    const dim3 gFoldC(15, NR);
    const int gE256 = (NE + 255)/256;
    const int gNH = (NN*HD + 255)/256;
    const int gSc = (NE + 3)/4;
    const int gSm = (NN*NH + 255)/256;
    const int gAg = (NN + 3)/4;

    // weight pre-pack to f16 fragment-major (once)
    k_w2f16<<<dim3(64, NT),       256,0,stream>>>(adapt_W, adaptF, 8);
    k_w2f16<<<dim3(64, NL*NT),    256,0,stream>>>(q_W, qF, 8);
    k_w2f16<<<dim3(64, NL*NT),    256,0,stream>>>(k_W, kF, 8);
    k_w2f16<<<dim3(64, NL*NT),    256,0,stream>>>(v_W, vF, 8);
    k_w2f16<<<dim3(64, NL*NT),    256,0,stream>>>(a_W, aF, 8);
    k_w2f16<<<dim3(1, NL*NR*NH),  256,0,stream>>>(rel_att, relAF, 5);
    k_w2f16<<<dim3(1, NL*NR*NH),  256,0,stream>>>(rel_msg, relMF, 5);

    // node buckets (by type)
    k_nhist<<<HBLK,256,0,stream>>>(node_type, nhist);
    k_nscan<<<1,64,0,stream>>>(nhist, noff, nbase);
    k_nscatter<<<HBLK,256,0,stream>>>(node_type, nbase, nbucket);

    // edge CSR sorted by tgt (parallel 3-phase scan)
    k_zero_bins<<<SCB,256,0,stream>>>(cnt);
    k_csr_hist<<<gE256,256,0,stream>>>(edge_index, cnt);
    k_scan1<<<SCB,256,0,stream>>>(cnt, tgt_off, bsum);
    k_scan2<<<1,128,0,stream>>>(bsum, bbase, tgt_off);
    k_scan3<<<SCB,256,0,stream>>>(tgt_off, bbase, binCur);
    k_csr_scatter<<<gE256,256,0,stream>>>(edge_index, edge_type, edge_time, node_type,
                                          binCur, src_s, combo_s, eid_s, tgt_s);

    // adapt: x = tanh(node_feature @ adapt_W[t] + b)
    k_typed_mfma<<<gTyp,256,0,stream>>>(node_feature, adaptF, nullptr, nullptr,
                                        adapt_b, nullptr, nullptr,
                                        xA, nullptr, nullptr,
                                        nbucket, noff, 1, 1, nullptr, nullptr);

    const float* x_in = xA;
    float* x_out = xB;
    for (int l = 0; l < NL; l++){
        k_row_gemm<<<dim3(MAXL,1),256,0,stream>>>(rte_emb, rte_W + (size_t)l*HD*HD,
                                                  rte_b + (size_t)l*HD, rteP, HD);
        k_row_gemm<<<dim3(MAXL,NT),256,0,stream>>>(rteP, k_W + (size_t)l*NT*HD*HD, nullptr, Kc, NT*HD);
        k_row_gemm<<<dim3(MAXL,NT),256,0,stream>>>(rteP, v_W + (size_t)l*NT*HD*HD, nullptr, Vc, NT*HD);
        // fused Q/K/V node-level GEMM (MFMA, A staged once)
        k_typed_mfma<<<gTyp,256,0,stream>>>(x_in,
                                            qF + (size_t)l*NT*HD*HD, kF + (size_t)l*NT*HD*HD, vF + (size_t)l*NT*HD*HD,
                                            q_b + (size_t)l*NT*HD,  k_b + (size_t)l*NT*HD,  v_b + (size_t)l*NT*HD,
                                            q0, k0, v0,
                                            nbucket, noff, 3, 0, nullptr, nullptr);
        // fold rel_att into node-level and combo-level tables (MFMA)
        k_fold_mfma<<<gFoldN,256,0,stream>>>(k0, relAF + (size_t)l*NR*NH*1024, (__half*)kavm, NN);
        k_fold_mfma<<<gFoldC,256,0,stream>>>(Kc, relAF + (size_t)l*NR*NH*1024, (__half*)kca, MAXL*NT);
        // scores + softmax
        k_score<<<gSc,256,0,stream>>>(q0, (__half*)kavm, (__half*)kca, rel_pri + (size_t)l*NR*NH,
                                      src_s, combo_s, tgt_s, s_arr);
        const int store_s = (l == NL-1) ? 1 : 0;
        k_softmax<<<gSm,256,0,stream>>>(s_arr, tgt_off, eid_s, out_att, store_s);
        // fold rel_msg, then aggregate (+gelu)
        k_fold_mfma<<<gFoldN,256,0,stream>>>(v0, relMF + (size_t)l*NR*NH*1024, (__half*)kavm, NN);
        k_fold_mfma<<<gFoldC,256,0,stream>>>(Vc, relMF + (size_t)l*NR*NH*1024, (__half*)kca, MAXL*NT);
        k_agg<<<gAg,256,0,stream>>>((__half*)kavm, (__half*)kca, s_arr, tgt_off, src_s, combo_s, agg);
        // output transform + skip
        k_typed_mfma<<<gTyp,256,0,stream>>>(agg, aF + (size_t)l*NT*HD*HD, nullptr, nullptr,
                                            a_b + (size_t)l*NT*HD, nullptr, nullptr,
                                            x_out, nullptr, nullptr,
                                            nbucket, noff, 1, 2, skip + (size_t)l*NT, x_in);
        float* tmp = (float*)x_in; x_in = x_out; x_out = tmp;
    }
    k_copy<<<gNH,256,0,stream>>>(x_in, out_x, NN*HD);
}